// Round 3
// baseline (105.429 us; speedup 1.0000x reference)
//
#include <hip/hip_runtime.h>
#include <math.h>

// Chamfer distance, B=4, H=W=128, HW=16384, threshold 0.1.
// ws layout (store path, needs ~19.5 MB):
//   [0,128)    int segcounts[8][4]
//   [256,+2MB) float4 pts[8][HW]   segmented semi-dense (seg s at s*4096)
//   [+512KB)   uint minarr[8][HW]  final per-slot d^2 bits (plain stores)
//   [+16.8MB)  float partial[8][NCHUNK][8192]  per-chunk row-min planes
// Fallback (ws < need): r2 atomic-combine path (same results).
//
// r2 post-mortem: occupancy 28->53% left dist at ~41us -> throughput wall,
// not latency. WRITE_SIZE 16282 KB == 4B per atomicMin: every atomic is a
// far (memory-side) op; ~22-25us occupancy-invariant drain tail (r1's
// LDS-free version: same atomics, same floor). Fix: replace cross-chunk
// atomicMin with plain-store partial planes + a parallel min-combine pass.
// Min-set identical -> minarr bits identical -> reduce_out unchanged.

#define B_ 4
#define HW_ 16384
#define THRESH 0.1f
#define BIGF 1e30f
#define EPS_ 1e-12f

#define NTHR 512       // dist: 8 waves/block
#define NCHUNK 64      // column chunks; also partial-plane count
#define MAXCHUNK 256   // ceil(HW/NCHUNK); cpad <= 256 always
#define SEGCAP 4096    // elements per compaction segment
#define NSEG 4
#define R_ST 16        // store path: rows/thread; 512x16 = all 8192 row slots
                       // in ONE pass (RSPLIT=1); DS amortization 16 pairs per
                       // ds_read -> DS pipe ~9.6us < VALU floor 16us
#define R_AT 8         // atomic fallback path (r2 config)
#define RSPLIT_AT 2

// Atomic-free compaction: one block per (segment, combo). 1024 thr x 4 elems,
// float4 loads; in-block prefix scan (wave shfl + LDS); actives written dense
// within the segment; per-seg count = plain store. minarr init via uint4
// (needed by atomic fallback only; harmless 0.5MB in store path).
__global__ __launch_bounds__(1024)
void compact_kernel(const float* __restrict__ in1, const float* __restrict__ in2,
                    int* __restrict__ segcounts, float4* __restrict__ pts,
                    uint4* __restrict__ minarr4) {
    int seg = blockIdx.x, combo = blockIdx.y;
    int b = combo >> 1, s = combo & 1;
    int tid = threadIdx.x, lane = tid & 63, wid = tid >> 6;
    const float* in = s ? in2 : in1;
    int ibase = seg * SEGCAP + tid * 4;              // element index in image
    float4 v = ((const float4*)(in + b * HW_))[(unsigned)ibase >> 2];
    float w0 = v.x - THRESH, w1 = v.y - THRESH, w2 = v.z - THRESH, w3 = v.w - THRESH;
    int a0 = w0 > 0.f, a1 = w1 > 0.f, a2 = w2 > 0.f, a3 = w3 > 0.f;

    unsigned int bb = __float_as_uint(BIGF);
    minarr4[(unsigned)(combo * HW_ + ibase) >> 2] = make_uint4(bb, bb, bb, bb);

    int c = a0 + a1 + a2 + a3;
    int incl = c;
#pragma unroll
    for (int o = 1; o < 64; o <<= 1) {
        int x = __shfl_up(incl, o, 64);
        if (lane >= o) incl += x;
    }
    int wexcl = incl - c;
    __shared__ int wtot[16], wpre[17];
    if (lane == 63) wtot[wid] = incl;
    __syncthreads();
    if (tid == 0) {
        int run = 0;
#pragma unroll
        for (int ww = 0; ww < 16; ++ww) { wpre[ww] = run; run += wtot[ww]; }
        wpre[16] = run;
    }
    __syncthreads();
    int off = wpre[wid] + wexcl;
    float4* dst = pts + combo * HW_ + seg * SEGCAP;
    float wv[4] = {w0, w1, w2, w3};
    int   av[4] = {a0, a1, a2, a3};
#pragma unroll
    for (int u = 0; u < 4; ++u) {
        if (av[u]) {
            int i = ibase + u;
            float qx = (float)(i >> 7) * wv[u];
            float qy = (float)(i & 127) * wv[u];
            dst[off] = make_float4(qx, qy, qx * qx + qy * qy, 0.0f);
            ++off;
        }
    }
    if (tid == 0) segcounts[combo * 4 + seg] = wpre[16];
}

// dense index r in [0, n) -> segmented slot, given prefix offsets o1<=o2<=o3.
__device__ __forceinline__ int map_slot(int r, int o1, int o2, int o3) {
    int slot = r;
    slot = (r >= o1) ? r - o1 + SEGCAP     : slot;
    slot = (r >= o2) ? r - o2 + 2 * SEGCAP : slot;
    slot = (r >= o3) ? r - o3 + 3 * SEGCAP : slot;
    return slot;
}

// STORE PATH dist: grid (NCHUNK, 8 combos), 512 thr, 4 waves/SIMD. Stage this
// block's to-chunk into LDS once; each thread min-reduces R_ST=16 rows (all
// 8192 row slots in one pass); per-row chunk-min written DENSE and coalesced
// to its partial plane -- no atomics anywhere.
__global__ __launch_bounds__(NTHR, 4)
void dist_store_kernel(const int* __restrict__ segcounts,
                       const float4* __restrict__ pts,
                       float* __restrict__ partial) {
    int chunk = blockIdx.x;
    int combo = blockIdx.y;
    int tid = threadIdx.x;
    int tc = combo ^ 1;
    int f1 = segcounts[combo * 4];
    int f2 = f1 + segcounts[combo * 4 + 1];
    int f3 = f2 + segcounts[combo * 4 + 2];
    int n_from = f3 + segcounts[combo * 4 + 3];
    int t1 = segcounts[tc * 4];
    int t2 = t1 + segcounts[tc * 4 + 1];
    int t3 = t2 + segcounts[tc * 4 + 2];
    int n_to = t3 + segcounts[tc * 4 + 3];
    if (n_from <= 0 || n_to <= 0) return;    // reduce_out emits sentinel anyway

    int len   = (n_to + NCHUNK - 1) / NCHUNK;
    int start = chunk * len;
    int end   = min(start + len, n_to);
    int clen  = end - start;

    float* __restrict__ pl = partial + (((size_t)combo * NCHUNK + chunk) << 13);

    if (clen <= 0) {                         // empty chunk: neutral plane
#pragma unroll
        for (int k = 0; k < R_ST; ++k) {
            int rd = tid + k * NTHR;
            if (rd < n_from) pl[rd] = BIGF;
        }
        return;
    }
    int cpad = (clen + 3) & ~3;              // <= MAXCHUNK always

    const float4* __restrict__ to   = pts + tc * HW_;
    const float4* __restrict__ from = pts + combo * HW_;

    __shared__ float4 buf[MAXCHUNK];
    if (tid < clen)
        buf[tid] = to[map_slot(start + tid, t1, t2, t3)];
    else if (tid < cpad)
        buf[tid] = make_float4(0.0f, 0.0f, BIGF, 0.0f);  // sentinel: never the min
    __syncthreads();

    float n2px[R_ST], n2py[R_ST], p2[R_ST], m[R_ST];
#pragma unroll
    for (int k = 0; k < R_ST; ++k) {
        int r = min(tid + k * NTHR, n_from - 1);     // clamp -> valid slot
        float4 p = from[map_slot(r, f1, f2, f3)];
        n2px[k] = -2.0f * p.x;
        n2py[k] = -2.0f * p.y;
        p2[k]   = p.z;
        m[k]    = BIGF;
    }
    for (int j = 0; j < cpad; j += 4) {      // quad-unroll, sentinel-padded
        float4 q0 = buf[j];                  // uniform addr -> LDS broadcast
        float4 q1 = buf[j + 1];
        float4 q2 = buf[j + 2];
        float4 q3 = buf[j + 3];
#pragma unroll
        for (int k = 0; k < R_ST; ++k) {
            float t0 = fmaf(q0.y, n2py[k], fmaf(q0.x, n2px[k], q0.z));
            float u1 = fmaf(q1.y, n2py[k], fmaf(q1.x, n2px[k], q1.z));
            m[k] = fminf(m[k], fminf(t0, u1));   // -> v_min3_f32
            float u2 = fmaf(q2.y, n2py[k], fmaf(q2.x, n2px[k], q2.z));
            float u3 = fmaf(q3.y, n2py[k], fmaf(q3.x, n2px[k], q3.z));
            m[k] = fminf(m[k], fminf(u2, u3));
        }
    }
#pragma unroll
    for (int k = 0; k < R_ST; ++k) {
        int rd = tid + k * NTHR;
        if (rd < n_from)                     // coalesced dense plain store
            pl[rd] = fmaxf(m[k] + p2[k], 0.0f);
    }
}

// Min-combine: grid (8192/256, 8 combos) = 256 blocks. Thread = one dense
// row; min over the 64 chunk planes (wave-coalesced per plane), store d^2
// bits to minarr[slot]. Same min-set as the atomic path -> identical bits.
__global__ __launch_bounds__(256)
void minc_kernel(const int* __restrict__ segcounts,
                 const float* __restrict__ partial,
                 unsigned int* __restrict__ minarr) {
    int combo = blockIdx.y;
    int r = blockIdx.x * 256 + threadIdx.x;
    int f1 = segcounts[combo * 4];
    int f2 = f1 + segcounts[combo * 4 + 1];
    int f3 = f2 + segcounts[combo * 4 + 2];
    int n_from = f3 + segcounts[combo * 4 + 3];
    if (r >= n_from) return;

    const float* __restrict__ pl = partial + (((size_t)combo * NCHUNK) << 13) + r;
    float m0 = BIGF, m1 = BIGF, m2 = BIGF, m3 = BIGF;   // 4 chains -> pipeline
#pragma unroll
    for (int c = 0; c < NCHUNK; c += 4) {
        m0 = fminf(m0, pl[(size_t)(c + 0) << 13]);
        m1 = fminf(m1, pl[(size_t)(c + 1) << 13]);
        m2 = fminf(m2, pl[(size_t)(c + 2) << 13]);
        m3 = fminf(m3, pl[(size_t)(c + 3) << 13]);
    }
    float mm = fminf(fminf(m0, m1), fminf(m2, m3));
    minarr[combo * HW_ + map_slot(r, f1, f2, f3)] = __float_as_uint(mm);
}

// ATOMIC FALLBACK dist (r2 config): used only when ws_size can't hold the
// partial planes. grid (NCHUNK, 8, RSPLIT_AT), 512 thr, 8 waves/SIMD.
__global__ __launch_bounds__(NTHR, 8)
void dist_atomic_kernel(const int* __restrict__ segcounts,
                        const float4* __restrict__ pts,
                        unsigned int* __restrict__ minarr) {
    int chunk = blockIdx.x;
    int combo = blockIdx.y;
    int tid = threadIdx.x;
    int tc = combo ^ 1;
    int f1 = segcounts[combo * 4];
    int f2 = f1 + segcounts[combo * 4 + 1];
    int f3 = f2 + segcounts[combo * 4 + 2];
    int n_from = f3 + segcounts[combo * 4 + 3];
    int t1 = segcounts[tc * 4];
    int t2 = t1 + segcounts[tc * 4 + 1];
    int t3 = t2 + segcounts[tc * 4 + 2];
    int n_to = t3 + segcounts[tc * 4 + 3];
    if (n_from <= 0 || n_to <= 0) return;

    int rbase = blockIdx.z * (NTHR * R_AT);
    if (rbase >= n_from) return;

    int len   = (n_to + NCHUNK - 1) / NCHUNK;
    int start = chunk * len;
    int end   = min(start + len, n_to);
    int clen  = end - start;
    if (clen <= 0) return;
    int cpad  = (clen + 3) & ~3;

    const float4* __restrict__ to   = pts + tc * HW_;
    const float4* __restrict__ from = pts + combo * HW_;

    __shared__ float4 buf[MAXCHUNK];
    if (tid < clen)
        buf[tid] = to[map_slot(start + tid, t1, t2, t3)];
    else if (tid < cpad)
        buf[tid] = make_float4(0.0f, 0.0f, BIGF, 0.0f);
    __syncthreads();

    int rd[R_AT], slot[R_AT];
    float n2px[R_AT], n2py[R_AT], p2[R_AT], m[R_AT];
#pragma unroll
    for (int k = 0; k < R_AT; ++k) {
        rd[k] = rbase + tid + k * NTHR;
        int r = min(rd[k], n_from - 1);
        slot[k] = map_slot(r, f1, f2, f3);
        float4 p = from[slot[k]];
        n2px[k] = -2.0f * p.x;
        n2py[k] = -2.0f * p.y;
        p2[k]   = p.z;
        m[k]    = BIGF;
    }
    for (int j = 0; j < cpad; j += 4) {
        float4 q0 = buf[j];
        float4 q1 = buf[j + 1];
        float4 q2 = buf[j + 2];
        float4 q3 = buf[j + 3];
#pragma unroll
        for (int k = 0; k < R_AT; ++k) {
            float t0 = fmaf(q0.y, n2py[k], fmaf(q0.x, n2px[k], q0.z));
            float u1 = fmaf(q1.y, n2py[k], fmaf(q1.x, n2px[k], q1.z));
            m[k] = fminf(m[k], fminf(t0, u1));
            float u2 = fmaf(q2.y, n2py[k], fmaf(q2.x, n2px[k], q2.z));
            float u3 = fmaf(q3.y, n2py[k], fmaf(q3.x, n2px[k], q3.z));
            m[k] = fminf(m[k], fminf(u2, u3));
        }
    }
#pragma unroll
    for (int k = 0; k < R_AT; ++k) {
        if (rd[k] < n_from) {
            float d2 = fmaxf(m[k] + p2[k], 0.0f);
            atomicMin(&minarr[combo * HW_ + slot[k]], __float_as_uint(d2));
        }
    }
}

// One 1024-thread block per batch; both directions reduced concurrently
// (tid<512 -> dir0, else dir1). Iterates segments directly (slot-indexed).
// UNCHANGED: summation order defines the absmax==0.0 baseline.
__global__ void reduce_out_kernel(const int* __restrict__ segcounts,
                                  const unsigned int* __restrict__ minarr,
                                  float* __restrict__ out) {
    int b = blockIdx.x;
    int tid = threadIdx.x;
    int d = tid >> 9;                            // 0 or 1
    int t = tid & 511;
    int combo = b * 2 + d;

    float acc = 0.0f;
    for (int s = 0; s < NSEG; ++s) {
        int c = segcounts[combo * 4 + s];
        const unsigned int* ma = minarr + combo * HW_ + s * SEGCAP;
        for (int r = t; r < c; r += 512)
            acc += sqrtf(fmaxf(__uint_as_float(ma[r]), EPS_));
    }
#pragma unroll
    for (int o = 32; o >= 1; o >>= 1) acc += __shfl_down(acc, o);

    __shared__ float wsum[16];                   // waves 0-7 dir0, 8-15 dir1
    if ((tid & 63) == 0) wsum[tid >> 6] = acc;
    __syncthreads();
    if (tid == 0) {
        float s0 = 0.0f, s1 = 0.0f;
#pragma unroll
        for (int w = 0; w < 8; ++w)  s0 += wsum[w];
#pragma unroll
        for (int w = 8; w < 16; ++w) s1 += wsum[w];
        int n0 = 0, n1 = 0;
#pragma unroll
        for (int s = 0; s < NSEG; ++s) {
            n0 += segcounts[(b * 2) * 4 + s];
            n1 += segcounts[(b * 2 + 1) * 4 + s];
        }
        out[b] = (n0 > 0 && n1 > 0)
                 ? s0 / (float)n0 + s1 / (float)n1
                 : 1.0e6f;
    }
}

extern "C" void kernel_launch(void* const* d_in, const int* in_sizes, int n_in,
                              void* d_out, int out_size, void* d_ws, size_t ws_size,
                              hipStream_t stream) {
    const float* in1 = (const float*)d_in[0];
    const float* in2 = (const float*)d_in[1];
    float* out = (float*)d_out;
    char* ws = (char*)d_ws;
    int* segcounts = (int*)ws;
    float4* pts = (float4*)(ws + 256);
    size_t minoff = 256 + (size_t)8 * HW_ * sizeof(float4);
    unsigned int* minarr = (unsigned int*)(ws + minoff);
    size_t paroff = minoff + (size_t)8 * HW_ * sizeof(unsigned int);
    float* partial = (float*)(ws + paroff);
    size_t need = paroff + (size_t)8 * NCHUNK * 8192 * sizeof(float);

    hipLaunchKernelGGL(compact_kernel, dim3(NSEG, 8), dim3(1024), 0, stream,
                       in1, in2, segcounts, pts, (uint4*)minarr);
    if (ws_size >= need) {
        hipLaunchKernelGGL(dist_store_kernel, dim3(NCHUNK, 8), dim3(NTHR), 0, stream,
                           segcounts, pts, partial);
        hipLaunchKernelGGL(minc_kernel, dim3(8192 / 256, 8), dim3(256), 0, stream,
                           segcounts, partial, minarr);
    } else {
        hipLaunchKernelGGL(dist_atomic_kernel, dim3(NCHUNK, 8, RSPLIT_AT),
                           dim3(NTHR), 0, stream, segcounts, pts, minarr);
    }
    hipLaunchKernelGGL(reduce_out_kernel, dim3(B_), dim3(1024), 0, stream,
                       segcounts, minarr, out);
}